// Round 4
// baseline (1094.496 us; speedup 1.0000x reference)
//
#include <hip/hip_runtime.h>
#include <math.h>

#define NBANDS 31
#define FT 257000

typedef __attribute__((ext_vector_type(8))) short bh8;
typedef __attribute__((ext_vector_type(4))) float f4;

__constant__ int d_bs[NBANDS] = {0,1,1,2,2,2,3,3,4,5,6,7,8,10,11,13,16,19,23,27,32,38,45,54,64,76,91,108,128,152,181};
__constant__ int d_be[NBANDS] = {2,3,3,3,4,4,5,6,7,8,9,11,12,14,17,20,24,28,33,39,46,55,65,77,92,109,129,153,182,216,257};

__device__ __forceinline__ unsigned short b16u(float v) {
  __bf16 h = (__bf16)v;
  return __builtin_bit_cast(unsigned short, h);
}
__device__ __forceinline__ unsigned pk2(float a, float b) {
  return (unsigned)b16u(a) | ((unsigned)b16u(b) << 16);
}
__device__ __forceinline__ float hann1(int i, int L) {
  return 0.5f - 0.5f * cosf(6.283185307179586f * (float)i / (float)L);
}

// ---- weight f32 -> bf16 prep into workspace ----
__global__ __launch_bounds__(256) void prep_w(
    const float* __restrict__ enc_w, const float* __restrict__ dec_w,
    const float* __restrict__ qw, const float* __restrict__ kw,
    const float* __restrict__ vw, const float* __restrict__ ow,
    unsigned short* __restrict__ w16) {
  const int stride = gridDim.x * blockDim.x;
  for (int i = blockIdx.x * blockDim.x + threadIdx.x; i < 513024; i += stride) {
    float v;
    if (i < 190464) v = enc_w[i];
    else if (i < 476160) v = dec_w[i - 190464];
    else {
      int j = i - 476160;
      int a = j / 9216, o = j - a * 9216;
      v = (a == 0) ? qw[o] : (a == 1) ? kw[o] : (a == 2) ? vw[o] : ow[o];
    }
    w16[i] = b16u(v);
  }
}

// ---- qp = doa @ dqg_w[k].T + dqg_b[k]; store (1+gamma | beta) ----
__global__ __launch_bounds__(192) void qp_kernel(const float* __restrict__ doa,
                                                 const float* __restrict__ dqg_w,
                                                 const float* __restrict__ dqg_b,
                                                 float* __restrict__ gbuf) {
  const int k = blockIdx.x, b = blockIdx.y;
  const int tid = threadIdx.x;
  __shared__ float sdoa[36];
  if (tid < 36) sdoa[tid] = doa[b * 36 + tid];
  __syncthreads();
  const float* wr = dqg_w + (k * 192 + tid) * 36;
  float acc = dqg_b[k * 192 + tid];
  #pragma unroll
  for (int i = 0; i < 36; ++i) acc = fmaf(wr[i], sdoa[i], acc);
  if (tid < 96) acc += 1.0f;
  gbuf[(k * 4 + b) * 192 + tid] = acc;
}

#define LDSWAIT asm volatile("s_waitcnt lgkmcnt(0)" ::: "memory")

// ---- fully fused MFMA kernel; 1D grid with XCD-contiguous (b,f) chunks ----
__global__ __launch_bounds__(256, 4) void fused_mfma(
    const float* __restrict__ mix, const float* __restrict__ spin,
    const unsigned short* __restrict__ enc16, const float* __restrict__ enc_b, const float* __restrict__ enc_a,
    const unsigned short* __restrict__ dec16, const float* __restrict__ dec_b, const float* __restrict__ dec_a,
    const float* __restrict__ gb,
    const unsigned short* __restrict__ q16, const float* __restrict__ qb,
    const unsigned short* __restrict__ k16, const float* __restrict__ kb,
    const unsigned short* __restrict__ v16, const float* __restrict__ vb,
    const unsigned short* __restrict__ o16, const float* __restrict__ ob,
    float* __restrict__ out) {
  // bijective XCD swizzle: 16448 = 8 * 2056; XCD k gets contiguous work ids
  const int id0 = (int)blockIdx.x;
  const int id  = (id0 & 7) * 2056 + (id0 >> 3);
  const int tt  = id & 15;
  const int fb  = id >> 4;
  const int f   = fb % 257;
  const int b   = fb / 257;
  const int t0  = tt << 6;

  const int tid  = threadIdx.x;
  const int lane = tid & 63;
  const int w    = tid >> 6;        // wave 0..3 owns cols [16w,16w+16)
  const int g    = lane >> 4;       // lane group 0..3
  const int n    = lane & 15;
  const int col  = (w << 4) + n;
  const int t    = t0 + col;
  const bool tv  = t < 1000;
  const int tcl  = tv ? t : 999;
  const int sw   = (n & 7) << 3;    // XOR swizzle (short units)

  __shared__ __align__(16) unsigned short XT[64 * 128];
  unsigned short* xw = XT + col * 128;

  float wsum = 0.f;
  for (int k = 0; k < NBANDS; ++k) {
    const int s = d_bs[k], e = d_be[k];
    if (f >= s && f < e) wsum += hann1(f - s, e - s);
  }
  const float winv = 1.0f / fmaxf(wsum, 1e-8f);

  const float* spL = spin + b * 64 * FT + f * 1000 + tcl;
  const float* mxL = mix  + b * 96 * FT + f * 1000 + tcl;

  // ---- prefetch spin (streaming: non-temporal), convert to B fragments ----
  bh8 spb[2];
  {
    float spf[16];
    #pragma unroll
    for (int j = 0; j < 8; ++j) spf[j]     = __builtin_nontemporal_load(spL + (g * 8 + j) * FT);
    #pragma unroll
    for (int j = 0; j < 8; ++j) spf[8 + j] = __builtin_nontemporal_load(spL + (32 + g * 8 + j) * FT);
    #pragma unroll
    for (int kt = 0; kt < 2; ++kt)
      #pragma unroll
      for (int j = 0; j < 8; ++j) spb[kt][j] = (short)b16u(spf[kt * 8 + j]);
  }

  f4 macc[6];
  #pragma unroll
  for (int mt = 0; mt < 6; ++mt) macc[mt] = (f4){0.f, 0.f, 0.f, 0.f};

  // ---------------- band loop ----------------
  for (int k = 0; k < NBANDS; ++k) {
    const int s = d_bs[k], e = d_be[k];
    if (f < s || f >= e) continue;
    const float win = hann1(f - s, e - s);

    // ---- enc: 96x64 ----
    f4 acc[6];
    #pragma unroll
    for (int mt = 0; mt < 6; ++mt) {
      const float4 bb = *reinterpret_cast<const float4*>(enc_b + k * 96 + mt * 16 + g * 4);
      acc[mt] = (f4){bb.x, bb.y, bb.z, bb.w};
    }
    const unsigned short* ew = enc16 + k * (96 * 64);
    #pragma unroll
    for (int kt = 0; kt < 2; ++kt)
      #pragma unroll
      for (int mt = 0; mt < 6; ++mt) {
        const bh8 af = *reinterpret_cast<const bh8*>(ew + (mt * 16 + n) * 64 + kt * 32 + g * 8);
        acc[mt] = __builtin_amdgcn_mfma_f32_16x16x32_bf16(af, spb[kt], acc[mt], 0, 0, 0);
      }
    // chan LN via shfl reduce
    float sm = 0.f, sq = 0.f;
    #pragma unroll
    for (int mt = 0; mt < 6; ++mt)
      #pragma unroll
      for (int r = 0; r < 4; ++r) { const float v = acc[mt][r]; sm += v; sq = fmaf(v, v, sq); }
    sm += __shfl_xor(sm, 16); sm += __shfl_xor(sm, 32);
    sq += __shfl_xor(sq, 16); sq += __shfl_xor(sq, 32);
    const float mean = sm * (1.f / 96.f);
    const float rs = rsqrtf(sq * (1.f / 96.f) - mean * mean + 1e-5f);
    const float ea = enc_a[k];
    const float* gbk = gb + (k * 4 + b) * 192;
    #pragma unroll
    for (int mt = 0; mt < 6; ++mt) {
      const float4 ga = *reinterpret_cast<const float4*>(gbk + mt * 16 + g * 4);
      const float4 be = *reinterpret_cast<const float4*>(gbk + 96 + mt * 16 + g * 4);
      float x0 = (acc[mt][0] - mean) * rs; x0 = (x0 >= 0.f) ? x0 : ea * x0;
      float x1 = (acc[mt][1] - mean) * rs; x1 = (x1 >= 0.f) ? x1 : ea * x1;
      float x2 = (acc[mt][2] - mean) * rs; x2 = (x2 >= 0.f) ? x2 : ea * x2;
      float x3 = (acc[mt][3] - mean) * rs; x3 = (x3 >= 0.f) ? x3 : ea * x3;
      uint2 u;
      u.x = pk2(fmaf(ga.x, x0, be.x), fmaf(ga.y, x1, be.y));
      u.y = pk2(fmaf(ga.z, x2, be.z), fmaf(ga.w, x3, be.w));
      *reinterpret_cast<uint2*>(xw + (((mt * 16 + g * 4)) ^ sw)) = u;
    }
    LDSWAIT;

    // ---- dec: 96x96 from XT ----
    f4 dacc[6];
    #pragma unroll
    for (int mt = 0; mt < 6; ++mt) {
      const float4 bb = *reinterpret_cast<const float4*>(dec_b + k * 96 + mt * 16 + g * 4);
      dacc[mt] = (f4){bb.x, bb.y, bb.z, bb.w};
    }
    const unsigned short* dwp = dec16 + k * (96 * 96);
    #pragma unroll
    for (int kt = 0; kt < 3; ++kt) {
      const bh8 bf = *reinterpret_cast<const bh8*>(xw + ((kt * 32 + g * 8) ^ sw));
      #pragma unroll
      for (int mt = 0; mt < 6; ++mt) {
        const bh8 af = *reinterpret_cast<const bh8*>(dwp + (mt * 16 + n) * 96 + kt * 32 + g * 8);
        dacc[mt] = __builtin_amdgcn_mfma_f32_16x16x32_bf16(af, bf, dacc[mt], 0, 0, 0);
      }
    }
    float sm2 = 0.f, sq2 = 0.f;
    #pragma unroll
    for (int mt = 0; mt < 6; ++mt)
      #pragma unroll
      for (int r = 0; r < 4; ++r) { const float v = dacc[mt][r]; sm2 += v; sq2 = fmaf(v, v, sq2); }
    sm2 += __shfl_xor(sm2, 16); sm2 += __shfl_xor(sm2, 32);
    sq2 += __shfl_xor(sq2, 16); sq2 += __shfl_xor(sq2, 32);
    const float mean2 = sm2 * (1.f / 96.f);
    const float rs2 = rsqrtf(sq2 * (1.f / 96.f) - mean2 * mean2 + 1e-5f);
    const float da = dec_a[k];
    #pragma unroll
    for (int mt = 0; mt < 6; ++mt)
      #pragma unroll
      for (int r = 0; r < 4; ++r) {
        float x = (dacc[mt][r] - mean2) * rs2;
        x = (x >= 0.f) ? x : da * x;
        macc[mt][r] = fmaf(win, x, macc[mt][r]);
      }
  }

  // ---- merged -> XT (bf16) ----
  #pragma unroll
  for (int mt = 0; mt < 6; ++mt) {
    uint2 u;
    u.x = pk2(macc[mt][0] * winv, macc[mt][1] * winv);
    u.y = pk2(macc[mt][2] * winv, macc[mt][3] * winv);
    *reinterpret_cast<uint2*>(xw + ((mt * 16 + g * 4) ^ sw)) = u;
  }
  LDSWAIT;
  bh8 gfr[3];
  #pragma unroll
  for (int kt = 0; kt < 3; ++kt) gfr[kt] = *reinterpret_cast<const bh8*>(xw + ((kt * 32 + g * 8) ^ sw));
  LDSWAIT;

  // ---- mix B-fragments (deferred; streaming non-temporal) ----
  bh8 mxb[3];
  {
    float mxf[24];
    #pragma unroll
    for (int kt = 0; kt < 3; ++kt)
      #pragma unroll
      for (int j = 0; j < 8; ++j) mxf[kt * 8 + j] = __builtin_nontemporal_load(mxL + (kt * 32 + g * 8 + j) * FT);
    #pragma unroll
    for (int kt = 0; kt < 3; ++kt)
      #pragma unroll
      for (int j = 0; j < 8; ++j) mxb[kt][j] = (short)b16u(mxf[kt * 8 + j]);
  }

  // ---- Q (mix), K (merged) ----
  f4 qacc[6];
  #pragma unroll
  for (int mt = 0; mt < 6; ++mt) {
    const float4 bb = *reinterpret_cast<const float4*>(qb + mt * 16 + g * 4);
    qacc[mt] = (f4){bb.x, bb.y, bb.z, bb.w};
  }
  #pragma unroll
  for (int kt = 0; kt < 3; ++kt)
    #pragma unroll
    for (int mt = 0; mt < 6; ++mt) {
      const bh8 af = *reinterpret_cast<const bh8*>(q16 + (mt * 16 + n) * 96 + kt * 32 + g * 8);
      qacc[mt] = __builtin_amdgcn_mfma_f32_16x16x32_bf16(af, mxb[kt], qacc[mt], 0, 0, 0);
    }
  f4 kacc[6];
  #pragma unroll
  for (int mt = 0; mt < 6; ++mt) {
    const float4 bb = *reinterpret_cast<const float4*>(kb + mt * 16 + g * 4);
    kacc[mt] = (f4){bb.x, bb.y, bb.z, bb.w};
  }
  #pragma unroll
  for (int kt = 0; kt < 3; ++kt)
    #pragma unroll
    for (int mt = 0; mt < 6; ++mt) {
      const bh8 af = *reinterpret_cast<const bh8*>(k16 + (mt * 16 + n) * 96 + kt * 32 + g * 8);
      kacc[mt] = __builtin_amdgcn_mfma_f32_16x16x32_bf16(af, gfr[kt], kacc[mt], 0, 0, 0);
    }
  float p = 0.f;
  #pragma unroll
  for (int mt = 0; mt < 6; ++mt)
    #pragma unroll
    for (int r = 0; r < 4; ++r) p = fmaf(qacc[mt][r], kacc[mt][r], p);
  p += __shfl_xor(p, 16); p += __shfl_xor(p, 32);
  const float sig = 1.f / (1.f + __expf(-p * 0.10206207261596575f));

  // residual (D-layout) — issue early so it hides under V/O MFMA; lines are L1/L2-hot
  float mres[6][4];
  #pragma unroll
  for (int mt = 0; mt < 6; ++mt)
    #pragma unroll
    for (int r = 0; r < 4; ++r) mres[mt][r] = mxL[(mt * 16 + g * 4 + r) * FT];

  // ---- V, attended -> XT ----
  f4 vacc[6];
  #pragma unroll
  for (int mt = 0; mt < 6; ++mt) {
    const float4 bb = *reinterpret_cast<const float4*>(vb + mt * 16 + g * 4);
    vacc[mt] = (f4){bb.x, bb.y, bb.z, bb.w};
  }
  #pragma unroll
  for (int kt = 0; kt < 3; ++kt)
    #pragma unroll
    for (int mt = 0; mt < 6; ++mt) {
      const bh8 af = *reinterpret_cast<const bh8*>(v16 + (mt * 16 + n) * 96 + kt * 32 + g * 8);
      vacc[mt] = __builtin_amdgcn_mfma_f32_16x16x32_bf16(af, gfr[kt], vacc[mt], 0, 0, 0);
    }
  #pragma unroll
  for (int mt = 0; mt < 6; ++mt) {
    uint2 u;
    u.x = pk2(vacc[mt][0] * sig, vacc[mt][1] * sig);
    u.y = pk2(vacc[mt][2] * sig, vacc[mt][3] * sig);
    *reinterpret_cast<uint2*>(xw + ((mt * 16 + g * 4) ^ sw)) = u;
  }
  LDSWAIT;

  // ---- O + residual ----
  f4 oacc[6];
  #pragma unroll
  for (int mt = 0; mt < 6; ++mt) {
    const float4 bb = *reinterpret_cast<const float4*>(ob + mt * 16 + g * 4);
    oacc[mt] = (f4){bb.x, bb.y, bb.z, bb.w};
  }
  #pragma unroll
  for (int kt = 0; kt < 3; ++kt) {
    const bh8 bf = *reinterpret_cast<const bh8*>(xw + ((kt * 32 + g * 8) ^ sw));
    #pragma unroll
    for (int mt = 0; mt < 6; ++mt) {
      const bh8 af = *reinterpret_cast<const bh8*>(o16 + (mt * 16 + n) * 96 + kt * 32 + g * 8);
      oacc[mt] = __builtin_amdgcn_mfma_f32_16x16x32_bf16(af, bf, oacc[mt], 0, 0, 0);
    }
  }
  if (tv) {
    #pragma unroll
    for (int mt = 0; mt < 6; ++mt) {
      const int base = (b * 96 + mt * 16 + g * 4) * FT + f * 1000 + t;
      #pragma unroll
      for (int r = 0; r < 4; ++r)
        __builtin_nontemporal_store(mres[mt][r] + oacc[mt][r], out + base + r * FT);
    }
  }
}

extern "C" void kernel_launch(void* const* d_in, const int* in_sizes, int n_in,
                              void* d_out, int out_size, void* d_ws, size_t ws_size,
                              hipStream_t stream) {
  (void)in_sizes; (void)n_in; (void)out_size; (void)ws_size;
  const float* mix   = (const float*)d_in[0];
  const float* spin  = (const float*)d_in[1];
  const float* doa   = (const float*)d_in[2];
  const float* enc_w = (const float*)d_in[3];
  const float* enc_b = (const float*)d_in[4];
  const float* enc_a = (const float*)d_in[5];
  const float* dqg_w = (const float*)d_in[6];
  const float* dqg_b = (const float*)d_in[7];
  const float* dec_w = (const float*)d_in[8];
  const float* dec_b = (const float*)d_in[9];
  const float* dec_a = (const float*)d_in[10];
  const float* qw    = (const float*)d_in[11];
  const float* qb    = (const float*)d_in[12];
  const float* kw    = (const float*)d_in[13];
  const float* kb    = (const float*)d_in[14];
  const float* vw    = (const float*)d_in[15];
  const float* vb    = (const float*)d_in[16];
  const float* oww   = (const float*)d_in[17];
  const float* obb   = (const float*)d_in[18];
  float* outp = (float*)d_out;

  unsigned short* w16 = (unsigned short*)d_ws;
  unsigned short* enc16 = w16;                 // 31*96*64   = 190464
  unsigned short* dec16 = w16 + 190464;        // 31*96*96   = 285696
  unsigned short* q16   = w16 + 476160;        // 9216 each
  unsigned short* k16   = q16 + 9216;
  unsigned short* v16   = k16 + 9216;
  unsigned short* o16   = v16 + 9216;
  float* gbws = (float*)((char*)d_ws + 1026048);  // 31*4*192 f32

  hipLaunchKernelGGL(prep_w, dim3(512), dim3(256), 0, stream,
                     enc_w, dec_w, qw, kw, vw, oww, w16);
  hipLaunchKernelGGL(qp_kernel, dim3(NBANDS, 4), dim3(192), 0, stream,
                     doa, dqg_w, dqg_b, gbws);
  hipLaunchKernelGGL(fused_mfma, dim3(16448), dim3(256), 0, stream,
                     mix, spin, enc16, enc_b, enc_a, dec16, dec_b, dec_a, gbws,
                     q16, qb, k16, kb, v16, vb, o16, obb, outp);
}

// Round 5
// 706.609 us; speedup vs baseline: 1.5489x; 1.5489x over previous
//
#include <hip/hip_runtime.h>
#include <math.h>

#define NBANDS 31
#define FT 257000

typedef __attribute__((ext_vector_type(8))) short bh8;
typedef __attribute__((ext_vector_type(4))) float f4;

__constant__ int d_bs[NBANDS] = {0,1,1,2,2,2,3,3,4,5,6,7,8,10,11,13,16,19,23,27,32,38,45,54,64,76,91,108,128,152,181};
__constant__ int d_be[NBANDS] = {2,3,3,3,4,4,5,6,7,8,9,11,12,14,17,20,24,28,33,39,46,55,65,77,92,109,129,153,182,216,257};

__device__ __forceinline__ unsigned short b16u(float v) {
  __bf16 h = (__bf16)v;
  return __builtin_bit_cast(unsigned short, h);
}
__device__ __forceinline__ unsigned pk2(float a, float b) {
  return (unsigned)b16u(a) | ((unsigned)b16u(b) << 16);
}
__device__ __forceinline__ float hann1(int i, int L) {
  return 0.5f - 0.5f * cosf(6.283185307179586f * (float)i / (float)L);
}

// ---- weight f32 -> bf16 prep, permuted into MFMA-fragment order ----
// tile layout: [tile][lane][8 shorts]; lane=(g*16+n) reads src (mt*16+n)*K + kt*32 + g*8 + j
__global__ __launch_bounds__(256) void prep_w(
    const float* __restrict__ enc_w, const float* __restrict__ dec_w,
    const float* __restrict__ qw, const float* __restrict__ kw,
    const float* __restrict__ vw, const float* __restrict__ ow,
    unsigned short* __restrict__ w16) {
  const int stride = gridDim.x * blockDim.x;
  for (int i = blockIdx.x * blockDim.x + threadIdx.x; i < 513024; i += stride) {
    float v;
    if (i < 190464) {                      // enc: K=64, KT=2, 6144/band
      const int k = i / 6144, r = i - k * 6144;
      const int tile = r >> 9, li = r & 511;
      const int lane = li >> 3, j = li & 7;
      const int g = lane >> 4, n = lane & 15;
      const int mt = tile >> 1, kt = tile & 1;
      v = enc_w[k * 6144 + (mt * 16 + n) * 64 + kt * 32 + g * 8 + j];
    } else if (i < 476160) {               // dec: K=96, KT=3, 9216/band
      const int i2 = i - 190464;
      const int k = i2 / 9216, r = i2 - k * 9216;
      const int tile = r >> 9, li = r & 511;
      const int lane = li >> 3, j = li & 7;
      const int g = lane >> 4, n = lane & 15;
      const int mt = tile / 3, kt = tile - mt * 3;
      v = dec_w[k * 9216 + (mt * 16 + n) * 96 + kt * 32 + g * 8 + j];
    } else {                               // q,k,v,o: K=96, KT=3, 9216 each
      const int i2 = i - 476160;
      const int a = i2 / 9216, r = i2 - a * 9216;
      const int tile = r >> 9, li = r & 511;
      const int lane = li >> 3, j = li & 7;
      const int g = lane >> 4, n = lane & 15;
      const int mt = tile / 3, kt = tile - mt * 3;
      const float* src = (a == 0) ? qw : (a == 1) ? kw : (a == 2) ? vw : ow;
      v = src[(mt * 16 + n) * 96 + kt * 32 + g * 8 + j];
    }
    w16[i] = b16u(v);
  }
}

// ---- qp = doa @ dqg_w[k].T + dqg_b[k]; store (1+gamma | beta) ----
__global__ __launch_bounds__(192) void qp_kernel(const float* __restrict__ doa,
                                                 const float* __restrict__ dqg_w,
                                                 const float* __restrict__ dqg_b,
                                                 float* __restrict__ gbuf) {
  const int k = blockIdx.x, b = blockIdx.y;
  const int tid = threadIdx.x;
  __shared__ float sdoa[36];
  if (tid < 36) sdoa[tid] = doa[b * 36 + tid];
  __syncthreads();
  const float* wr = dqg_w + (k * 192 + tid) * 36;
  float acc = dqg_b[k * 192 + tid];
  #pragma unroll
  for (int i = 0; i < 36; ++i) acc = fmaf(wr[i], sdoa[i], acc);
  if (tid < 96) acc += 1.0f;
  gbuf[(k * 4 + b) * 192 + tid] = acc;
}

#define LDSWAIT asm volatile("s_waitcnt lgkmcnt(0)" ::: "memory")

// ---- fully fused MFMA kernel; fragment-ordered weights; 1D grid XCD swizzle ----
__global__ __launch_bounds__(256, 4) void fused_mfma(
    const float* __restrict__ mix, const float* __restrict__ spin,
    const unsigned short* __restrict__ enc16, const float* __restrict__ enc_b, const float* __restrict__ enc_a,
    const unsigned short* __restrict__ dec16, const float* __restrict__ dec_b, const float* __restrict__ dec_a,
    const float* __restrict__ gb,
    const unsigned short* __restrict__ q16, const float* __restrict__ qb,
    const unsigned short* __restrict__ k16, const float* __restrict__ kb,
    const unsigned short* __restrict__ v16, const float* __restrict__ vb,
    const unsigned short* __restrict__ o16, const float* __restrict__ ob,
    float* __restrict__ out) {
  const int id0 = (int)blockIdx.x;
  const int id  = (id0 & 7) * 2056 + (id0 >> 3);   // bijective XCD swizzle (16448 = 8*2056)
  const int tt  = id & 15;
  const int fb  = id >> 4;
  const int f   = fb % 257;
  const int b   = fb / 257;
  const int t0  = tt << 6;

  const int tid  = threadIdx.x;
  const int lane = tid & 63;
  const int w    = tid >> 6;
  const int g    = lane >> 4;
  const int n    = lane & 15;
  const int col  = (w << 4) + n;
  const int t    = t0 + col;
  const bool tv  = t < 1000;
  const int tcl  = tv ? t : 999;
  const int sw   = (n & 7) << 3;
  const int lb   = lane << 3;          // fragment byte offset /2

  __shared__ __align__(16) unsigned short XT[64 * 128];
  unsigned short* xw = XT + col * 128;

  float wsum = 0.f;
  for (int k = 0; k < NBANDS; ++k) {
    const int s = d_bs[k], e = d_be[k];
    if (f >= s && f < e) wsum += hann1(f - s, e - s);
  }
  const float winv = 1.0f / fmaxf(wsum, 1e-8f);

  const float* spL = spin + b * 64 * FT + f * 1000 + tcl;
  const float* mxL = mix  + b * 96 * FT + f * 1000 + tcl;

  // ---- prefetch spin (read-once: non-temporal), convert to B fragments ----
  bh8 spb[2];
  {
    float spf[16];
    #pragma unroll
    for (int j = 0; j < 8; ++j) spf[j]     = __builtin_nontemporal_load(spL + (g * 8 + j) * FT);
    #pragma unroll
    for (int j = 0; j < 8; ++j) spf[8 + j] = __builtin_nontemporal_load(spL + (32 + g * 8 + j) * FT);
    #pragma unroll
    for (int kt = 0; kt < 2; ++kt)
      #pragma unroll
      for (int j = 0; j < 8; ++j) spb[kt][j] = (short)b16u(spf[kt * 8 + j]);
  }

  f4 macc[6];
  #pragma unroll
  for (int mt = 0; mt < 6; ++mt) macc[mt] = (f4){0.f, 0.f, 0.f, 0.f};

  // ---------------- band loop ----------------
  for (int k = 0; k < NBANDS; ++k) {
    const int s = d_bs[k], e = d_be[k];
    if (f < s || f >= e) continue;
    const float win = hann1(f - s, e - s);

    // ---- enc: 96x64 (fragment-ordered, coalesced) ----
    f4 acc[6];
    #pragma unroll
    for (int mt = 0; mt < 6; ++mt) {
      const float4 bb = *reinterpret_cast<const float4*>(enc_b + k * 96 + mt * 16 + g * 4);
      acc[mt] = (f4){bb.x, bb.y, bb.z, bb.w};
    }
    const unsigned short* ew = enc16 + k * 6144 + lb;
    #pragma unroll
    for (int kt = 0; kt < 2; ++kt)
      #pragma unroll
      for (int mt = 0; mt < 6; ++mt) {
        const bh8 af = *reinterpret_cast<const bh8*>(ew + ((mt * 2 + kt) << 9));
        acc[mt] = __builtin_amdgcn_mfma_f32_16x16x32_bf16(af, spb[kt], acc[mt], 0, 0, 0);
      }
    // chan LN via shfl reduce
    float sm = 0.f, sq = 0.f;
    #pragma unroll
    for (int mt = 0; mt < 6; ++mt)
      #pragma unroll
      for (int r = 0; r < 4; ++r) { const float v = acc[mt][r]; sm += v; sq = fmaf(v, v, sq); }
    sm += __shfl_xor(sm, 16); sm += __shfl_xor(sm, 32);
    sq += __shfl_xor(sq, 16); sq += __shfl_xor(sq, 32);
    const float mean = sm * (1.f / 96.f);
    const float rs = rsqrtf(sq * (1.f / 96.f) - mean * mean + 1e-5f);
    const float ea = enc_a[k];
    const float* gbk = gb + (k * 4 + b) * 192;
    #pragma unroll
    for (int mt = 0; mt < 6; ++mt) {
      const float4 ga = *reinterpret_cast<const float4*>(gbk + mt * 16 + g * 4);
      const float4 be = *reinterpret_cast<const float4*>(gbk + 96 + mt * 16 + g * 4);
      float x0 = (acc[mt][0] - mean) * rs; x0 = (x0 >= 0.f) ? x0 : ea * x0;
      float x1 = (acc[mt][1] - mean) * rs; x1 = (x1 >= 0.f) ? x1 : ea * x1;
      float x2 = (acc[mt][2] - mean) * rs; x2 = (x2 >= 0.f) ? x2 : ea * x2;
      float x3 = (acc[mt][3] - mean) * rs; x3 = (x3 >= 0.f) ? x3 : ea * x3;
      uint2 u;
      u.x = pk2(fmaf(ga.x, x0, be.x), fmaf(ga.y, x1, be.y));
      u.y = pk2(fmaf(ga.z, x2, be.z), fmaf(ga.w, x3, be.w));
      *reinterpret_cast<uint2*>(xw + (((mt * 16 + g * 4)) ^ sw)) = u;
    }
    LDSWAIT;

    // ---- dec: 96x96 from XT ----
    f4 dacc[6];
    #pragma unroll
    for (int mt = 0; mt < 6; ++mt) {
      const float4 bb = *reinterpret_cast<const float4*>(dec_b + k * 96 + mt * 16 + g * 4);
      dacc[mt] = (f4){bb.x, bb.y, bb.z, bb.w};
    }
    const unsigned short* dwp = dec16 + k * 9216 + lb;
    #pragma unroll
    for (int kt = 0; kt < 3; ++kt) {
      const bh8 bf = *reinterpret_cast<const bh8*>(xw + ((kt * 32 + g * 8) ^ sw));
      #pragma unroll
      for (int mt = 0; mt < 6; ++mt) {
        const bh8 af = *reinterpret_cast<const bh8*>(dwp + ((mt * 3 + kt) << 9));
        dacc[mt] = __builtin_amdgcn_mfma_f32_16x16x32_bf16(af, bf, dacc[mt], 0, 0, 0);
      }
    }
    float sm2 = 0.f, sq2 = 0.f;
    #pragma unroll
    for (int mt = 0; mt < 6; ++mt)
      #pragma unroll
      for (int r = 0; r < 4; ++r) { const float v = dacc[mt][r]; sm2 += v; sq2 = fmaf(v, v, sq2); }
    sm2 += __shfl_xor(sm2, 16); sm2 += __shfl_xor(sm2, 32);
    sq2 += __shfl_xor(sq2, 16); sq2 += __shfl_xor(sq2, 32);
    const float mean2 = sm2 * (1.f / 96.f);
    const float rs2 = rsqrtf(sq2 * (1.f / 96.f) - mean2 * mean2 + 1e-5f);
    const float da = dec_a[k];
    #pragma unroll
    for (int mt = 0; mt < 6; ++mt)
      #pragma unroll
      for (int r = 0; r < 4; ++r) {
        float x = (dacc[mt][r] - mean2) * rs2;
        x = (x >= 0.f) ? x : da * x;
        macc[mt][r] = fmaf(win, x, macc[mt][r]);
      }
  }

  // ---- merged -> XT (bf16) ----
  #pragma unroll
  for (int mt = 0; mt < 6; ++mt) {
    uint2 u;
    u.x = pk2(macc[mt][0] * winv, macc[mt][1] * winv);
    u.y = pk2(macc[mt][2] * winv, macc[mt][3] * winv);
    *reinterpret_cast<uint2*>(xw + ((mt * 16 + g * 4) ^ sw)) = u;
  }
  LDSWAIT;
  bh8 gfr[3];
  #pragma unroll
  for (int kt = 0; kt < 3; ++kt) gfr[kt] = *reinterpret_cast<const bh8*>(xw + ((kt * 32 + g * 8) ^ sw));
  LDSWAIT;

  // ---- mix B-fragments (cached: residual re-read must hit L2) ----
  bh8 mxb[3];
  {
    float mxf[24];
    #pragma unroll
    for (int kt = 0; kt < 3; ++kt)
      #pragma unroll
      for (int j = 0; j < 8; ++j) mxf[kt * 8 + j] = mxL[(kt * 32 + g * 8 + j) * FT];
    #pragma unroll
    for (int kt = 0; kt < 3; ++kt)
      #pragma unroll
      for (int j = 0; j < 8; ++j) mxb[kt][j] = (short)b16u(mxf[kt * 8 + j]);
  }

  // ---- Q (mix), K (merged) ----
  f4 qacc[6];
  #pragma unroll
  for (int mt = 0; mt < 6; ++mt) {
    const float4 bb = *reinterpret_cast<const float4*>(qb + mt * 16 + g * 4);
    qacc[mt] = (f4){bb.x, bb.y, bb.z, bb.w};
  }
  const unsigned short* qp16 = q16 + lb;
  #pragma unroll
  for (int kt = 0; kt < 3; ++kt)
    #pragma unroll
    for (int mt = 0; mt < 6; ++mt) {
      const bh8 af = *reinterpret_cast<const bh8*>(qp16 + ((mt * 3 + kt) << 9));
      qacc[mt] = __builtin_amdgcn_mfma_f32_16x16x32_bf16(af, mxb[kt], qacc[mt], 0, 0, 0);
    }
  f4 kacc[6];
  #pragma unroll
  for (int mt = 0; mt < 6; ++mt) {
    const float4 bb = *reinterpret_cast<const float4*>(kb + mt * 16 + g * 4);
    kacc[mt] = (f4){bb.x, bb.y, bb.z, bb.w};
  }
  const unsigned short* kp16 = k16 + lb;
  #pragma unroll
  for (int kt = 0; kt < 3; ++kt)
    #pragma unroll
    for (int mt = 0; mt < 6; ++mt) {
      const bh8 af = *reinterpret_cast<const bh8*>(kp16 + ((mt * 3 + kt) << 9));
      kacc[mt] = __builtin_amdgcn_mfma_f32_16x16x32_bf16(af, gfr[kt], kacc[mt], 0, 0, 0);
    }
  float p = 0.f;
  #pragma unroll
  for (int mt = 0; mt < 6; ++mt)
    #pragma unroll
    for (int r = 0; r < 4; ++r) p = fmaf(qacc[mt][r], kacc[mt][r], p);
  p += __shfl_xor(p, 16); p += __shfl_xor(p, 32);
  const float sig = 1.f / (1.f + __expf(-p * 0.10206207261596575f));

  // residual (D-layout) — issue early; hides under V/O MFMA
  float mres[6][4];
  #pragma unroll
  for (int mt = 0; mt < 6; ++mt)
    #pragma unroll
    for (int r = 0; r < 4; ++r) mres[mt][r] = mxL[(mt * 16 + g * 4 + r) * FT];

  // ---- V, attended -> XT ----
  f4 vacc[6];
  #pragma unroll
  for (int mt = 0; mt < 6; ++mt) {
    const float4 bb = *reinterpret_cast<const float4*>(vb + mt * 16 + g * 4);
    vacc[mt] = (f4){bb.x, bb.y, bb.z, bb.w};
  }
  const unsigned short* vp16 = v16 + lb;
  #pragma unroll
  for (int kt = 0; kt < 3; ++kt)
    #pragma unroll
    for (int mt = 0; mt < 6; ++mt) {
      const bh8 af = *reinterpret_cast<const bh8*>(vp16 + ((mt * 3 + kt) << 9));
      vacc[mt] = __builtin_amdgcn_mfma_f32_16x16x32_bf16(af, gfr[kt], vacc[mt], 0, 0, 0);
    }
  #pragma unroll
  for (int mt = 0; mt < 6; ++mt) {
    uint2 u;
    u.x = pk2(vacc[mt][0] * sig, vacc[mt][1] * sig);
    u.y = pk2(vacc[mt][2] * sig, vacc[mt][3] * sig);
    *reinterpret_cast<uint2*>(xw + ((mt * 16 + g * 4) ^ sw)) = u;
  }
  LDSWAIT;

  // ---- O + residual ----
  f4 oacc[6];
  #pragma unroll
  for (int mt = 0; mt < 6; ++mt) {
    const float4 bb = *reinterpret_cast<const float4*>(ob + mt * 16 + g * 4);
    oacc[mt] = (f4){bb.x, bb.y, bb.z, bb.w};
  }
  const unsigned short* op16 = o16 + lb;
  #pragma unroll
  for (int kt = 0; kt < 3; ++kt) {
    const bh8 bf = *reinterpret_cast<const bh8*>(xw + ((kt * 32 + g * 8) ^ sw));
    #pragma unroll
    for (int mt = 0; mt < 6; ++mt) {
      const bh8 af = *reinterpret_cast<const bh8*>(op16 + ((mt * 3 + kt) << 9));
      oacc[mt] = __builtin_amdgcn_mfma_f32_16x16x32_bf16(af, bf, oacc[mt], 0, 0, 0);
    }
  }
  if (tv) {
    #pragma unroll
    for (int mt = 0; mt < 6; ++mt) {
      const int base = (b * 96 + mt * 16 + g * 4) * FT + f * 1000 + t;
      #pragma unroll
      for (int r = 0; r < 4; ++r)
        __builtin_nontemporal_store(mres[mt][r] + oacc[mt][r], out + base + r * FT);
    }
  }
}

extern "C" void kernel_launch(void* const* d_in, const int* in_sizes, int n_in,
                              void* d_out, int out_size, void* d_ws, size_t ws_size,
                              hipStream_t stream) {
  (void)in_sizes; (void)n_in; (void)out_size; (void)ws_size;
  const float* mix   = (const float*)d_in[0];
  const float* spin  = (const float*)d_in[1];
  const float* doa   = (const float*)d_in[2];
  const float* enc_w = (const float*)d_in[3];
  const float* enc_b = (const float*)d_in[4];
  const float* enc_a = (const float*)d_in[5];
  const float* dqg_w = (const float*)d_in[6];
  const float* dqg_b = (const float*)d_in[7];
  const float* dec_w = (const float*)d_in[8];
  const float* dec_b = (const float*)d_in[9];
  const float* dec_a = (const float*)d_in[10];
  const float* qw    = (const float*)d_in[11];
  const float* qb    = (const float*)d_in[12];
  const float* kw    = (const float*)d_in[13];
  const float* kb    = (const float*)d_in[14];
  const float* vw    = (const float*)d_in[15];
  const float* vb    = (const float*)d_in[16];
  const float* oww   = (const float*)d_in[17];
  const float* obb   = (const float*)d_in[18];
  float* outp = (float*)d_out;

  unsigned short* w16 = (unsigned short*)d_ws;
  unsigned short* enc16 = w16;                 // 31*6144
  unsigned short* dec16 = w16 + 190464;        // 31*9216
  unsigned short* q16   = w16 + 476160;
  unsigned short* k16   = q16 + 9216;
  unsigned short* v16   = k16 + 9216;
  unsigned short* o16   = v16 + 9216;
  float* gbws = (float*)((char*)d_ws + 1026048);  // 31*4*192 f32

  hipLaunchKernelGGL(prep_w, dim3(512), dim3(256), 0, stream,
                     enc_w, dec_w, qw, kw, vw, oww, w16);
  hipLaunchKernelGGL(qp_kernel, dim3(NBANDS, 4), dim3(192), 0, stream,
                     doa, dqg_w, dqg_b, gbws);
  hipLaunchKernelGGL(fused_mfma, dim3(16448), dim3(256), 0, stream,
                     mix, spin, enc16, enc_b, enc_a, dec16, dec_b, dec_a, gbws,
                     q16, qb, k16, kb, v16, vb, o16, obb, outp);
}